// Round 8
// baseline (589.818 us; speedup 1.0000x reference)
//
#include <hip/hip_runtime.h>
#include <hip/hip_bf16.h>

typedef __attribute__((ext_vector_type(8))) short short8;
typedef __attribute__((ext_vector_type(4))) float f32x4;
typedef unsigned short ushort_t;
typedef unsigned int uint_t;

#define D_MODEL 512
#define D_ATTN  64
#define BIAS_BLOCKS 4096   // 4 wave-halfrows each -> 16384 halfrows = 8192 rows
#define QKV_BLOCKS  512    // 16 rows each

__device__ __forceinline__ ushort_t f2bf(float f) {
    // round-to-nearest-even bf16 (finite inputs)
    uint_t u = __float_as_uint(f);
    u += 0x7FFFu + ((u >> 16) & 1u);
    return (ushort_t)(u >> 16);
}
__device__ __forceinline__ float bf2f(ushort_t h) {
    return __uint_as_float((uint_t)h << 16);
}
__device__ __forceinline__ f32x4 ntload4(const f32x4* p) {
    return __builtin_nontemporal_load(p);   // top read once; keep L3 for bias/QKV
}

// ------- Kernel A: lean high-occupancy bias stream + qkv tail blocks -------
// bias path: no LDS, ~30 VGPR -> ~24 waves/CU of independent lean streams.
__global__ __launch_bounds__(256, 6)
void fused_bias_qkv(const float* __restrict__ x, const float* __restrict__ top,
                    const float* __restrict__ Wq, const float* __restrict__ bq,
                    const float* __restrict__ Wk, const float* __restrict__ bk,
                    const float* __restrict__ Wv, const float* __restrict__ bv,
                    const float* __restrict__ Wt,
                    ushort_t* __restrict__ Q, ushort_t* __restrict__ K,
                    ushort_t* __restrict__ Vt, ushort_t* __restrict__ bias)
{
    const int tid = threadIdx.x;
    const int l = tid & 63, w = tid >> 6;

    if (blockIdx.x < BIAS_BLOCKS) {
        // ---- bias: wave owns one contiguous 32KB half-row (512 outputs) ----
        const int h   = (blockIdx.x << 2) + w;   // halfrow id 0..16383
        const int row = h >> 1;                  // global (b*1024+n) 0..8191
        const int half = h & 1;
        const f32x4* __restrict__ gp =
            (const f32x4*)(top + ((size_t)row << 14) + ((size_t)half << 13)) + l;
        ushort_t* __restrict__ op = bias + ((size_t)row << 10) + (half << 9);
        const float4 wq = *(const float4*)(Wt + ((l & 3) << 2));  // my Wt quarter
        const int mq = l >> 2;
        const bool sel0 = (l & 3) == 0;
#pragma unroll 4
        for (int it = 0; it < 32; ++it) {
            f32x4 v = ntload4(gp + (it << 6));   // 64 lanes x 16B = 1KB contiguous
            float p = v[0] * wq.x;
            p = fmaf(v[1], wq.y, p);
            p = fmaf(v[2], wq.z, p);
            p = fmaf(v[3], wq.w, p);
            p += __shfl_xor(p, 1);               // fold quarters in 4-lane group
            p += __shfl_xor(p, 2);
            if (sel0) op[(it << 4) + mq] = f2bf(p);
        }
        // bt dropped: softmax shift-invariant
    } else {
        // ---- qkv (R4-verified body): 16 rows/block, wave w -> rows 4w..4w+3 ----
        const size_t bn0 = (size_t)(blockIdx.x - BIAS_BLOCKS) << 4;
        const int r0 = w << 2;
        const float* xb = x + (bn0 + r0) * D_MODEL;
        { uintptr_t u = (uintptr_t)xb; asm volatile("" : "+v"(u)); xb = (const float*)u; }

        float aq[4] = {0,0,0,0}, ak[4] = {0,0,0,0}, av[4] = {0,0,0,0};
#pragma unroll 2
        for (int k = 0; k < D_MODEL; k += 4) {
            float4 xr[4];
#pragma unroll
            for (int r = 0; r < 4; ++r) xr[r] = *(const float4*)(xb + r * D_MODEL + k);
            float wqv[4], wkv[4], wvv[4];
#pragma unroll
            for (int kk = 0; kk < 4; ++kk) {
                wqv[kk] = Wq[(k + kk) * D_ATTN + l];
                wkv[kk] = Wk[(k + kk) * D_ATTN + l];
                wvv[kk] = Wv[(k + kk) * D_ATTN + l];
            }
#pragma unroll
            for (int r = 0; r < 4; ++r) {
                const float xv[4] = {xr[r].x, xr[r].y, xr[r].z, xr[r].w};
#pragma unroll
                for (int kk = 0; kk < 4; ++kk) {
                    aq[r] = fmaf(xv[kk], wqv[kk], aq[r]);
                    ak[r] = fmaf(xv[kk], wkv[kk], ak[r]);
                    av[r] = fmaf(xv[kk], wvv[kk], av[r]);
                }
            }
        }
        const float bqv = bq[l], bkv = bk[l], bvv = bv[l];
#pragma unroll
        for (int r = 0; r < 4; ++r) {
            Q[(bn0 + r0 + r) * D_ATTN + l] = f2bf((aq[r] + bqv) * 0.125f); // fold 1/sqrt(64)
            K[(bn0 + r0 + r) * D_ATTN + l] = f2bf(ak[r] + bkv);
        }
        const int b = (int)(bn0 >> 10), n0loc = (int)(bn0 & 1023);
        uint2 pv;
        pv.x = (uint_t)f2bf(av[0] + bvv) | ((uint_t)f2bf(av[1] + bvv) << 16);
        pv.y = (uint_t)f2bf(av[2] + bvv) | ((uint_t)f2bf(av[3] + bvv) << 16);
        *(uint2*)(Vt + ((size_t)(b * 64 + l) << 10) + n0loc + r0) = pv;
    }
}

// ---------------- Kernel B: attention from precomputed bias (R2-verified) ----------------
__global__ __launch_bounds__(256)
void topo_attn(const ushort_t* __restrict__ bias,
               const ushort_t* __restrict__ Q, const ushort_t* __restrict__ K,
               const ushort_t* __restrict__ Vt, float* __restrict__ out)
{
    __shared__ float lds[16384];
    const int tid = threadIdx.x;
    const int b   = blockIdx.x >> 6;
    const int bn0 = blockIdx.x << 4;   // b*1024 + n0

    // ---- Phase A': bias bf16 -> LDS logits f32 ----
    const ushort_t* __restrict__ bb = bias + ((size_t)bn0 << 10);
#pragma unroll
    for (int it = 0; it < 8; ++it) {
        int e0 = (it << 11) + (tid << 3);
        short8 v = *(const short8*)(bb + e0);
        f32x4 f0, f1;
#pragma unroll
        for (int j = 0; j < 4; ++j) f0[j] = bf2f((ushort_t)v[j]);
#pragma unroll
        for (int j = 0; j < 4; ++j) f1[j] = bf2f((ushort_t)v[4 + j]);
        *(f32x4*)(lds + e0)     = f0;
        *(f32x4*)(lds + e0 + 4) = f1;
    }
    __syncthreads();

    // ---- Phase B: logits += (Q/8) K^T via MFMA ----
    const int l = tid & 63, wv = tid >> 6;
    const int lr = l & 15, lg = l >> 4;
    const short8 a0 = *(const short8*)(Q + ((size_t)(bn0 + lr)) * 64 + 8 * lg);
    const short8 a1 = *(const short8*)(Q + ((size_t)(bn0 + lr)) * 64 + 32 + 8 * lg);
    const ushort_t* __restrict__ Kb = K + ((size_t)b << 16);
#pragma unroll 4
    for (int t16 = 0; t16 < 16; ++t16) {
        int m0 = (wv << 8) + (t16 << 4);
        short8 kb0 = *(const short8*)(Kb + (size_t)(m0 + lr) * 64 + 8 * lg);
        short8 kb1 = *(const short8*)(Kb + (size_t)(m0 + lr) * 64 + 32 + 8 * lg);
        f32x4 acc = {0.f, 0.f, 0.f, 0.f};
        acc = __builtin_amdgcn_mfma_f32_16x16x32_bf16(a0, kb0, acc, 0, 0, 0);
        acc = __builtin_amdgcn_mfma_f32_16x16x32_bf16(a1, kb1, acc, 0, 0, 0);
#pragma unroll
        for (int j = 0; j < 4; ++j)
            lds[(4 * lg + j) * 1024 + m0 + lr] += acc[j];  // C/D: col=lane&15, row=4*(l>>4)+j
    }
    __syncthreads();

    // ---- Phase C: row softmax; write P (bf16) aliased over logits[0:32KB) ----
    {
        const int r = tid >> 4, sseg = tid & 15;
        float4 v4[16];
        const float4* rowp = (const float4*)(lds + r * 1024 + sseg * 64);
#pragma unroll
        for (int i = 0; i < 16; ++i) v4[i] = rowp[i];
        __syncthreads();   // everyone finished reading logits before alias overwrite
        float mx = v4[0].x;
#pragma unroll
        for (int i = 0; i < 16; ++i)
            mx = fmaxf(mx, fmaxf(fmaxf(v4[i].x, v4[i].y), fmaxf(v4[i].z, v4[i].w)));
#pragma unroll
        for (int off = 8; off >= 1; off >>= 1) mx = fmaxf(mx, __shfl_xor(mx, off));
        float sum = 0.f;
#pragma unroll
        for (int i = 0; i < 16; ++i) {
            v4[i].x = __expf(v4[i].x - mx); sum += v4[i].x;
            v4[i].y = __expf(v4[i].y - mx); sum += v4[i].y;
            v4[i].z = __expf(v4[i].z - mx); sum += v4[i].z;
            v4[i].w = __expf(v4[i].w - mx); sum += v4[i].w;
        }
#pragma unroll
        for (int off = 8; off >= 1; off >>= 1) sum += __shfl_xor(sum, off);
        float inv = 1.0f / sum;
        ushort_t* pb = ((ushort_t*)lds) + r * 1024 + sseg * 64;
#pragma unroll
        for (int i = 0; i < 8; ++i) {
            uint_t w0 = (uint_t)f2bf(v4[2*i].x * inv)   | ((uint_t)f2bf(v4[2*i].y * inv)   << 16);
            uint_t w1 = (uint_t)f2bf(v4[2*i].z * inv)   | ((uint_t)f2bf(v4[2*i].w * inv)   << 16);
            uint_t w2 = (uint_t)f2bf(v4[2*i+1].x * inv) | ((uint_t)f2bf(v4[2*i+1].y * inv) << 16);
            uint_t w3 = (uint_t)f2bf(v4[2*i+1].z * inv) | ((uint_t)f2bf(v4[2*i+1].w * inv) << 16);
            ((uint4*)pb)[i] = make_uint4(w0, w1, w2, w3);
        }
    }
    __syncthreads();

    // ---- Phase D: out = P V  (V transposed -> contiguous B-frag loads) ----
    {
        f32x4 o[4] = {{0,0,0,0},{0,0,0,0},{0,0,0,0},{0,0,0,0}};
        const ushort_t* __restrict__ pb = ((const ushort_t*)lds) + lr * 1024;
        const ushort_t* __restrict__ Vb = Vt + ((size_t)b << 16);
#pragma unroll 2
        for (int c = 0; c < 8; ++c) {
            int m0 = (wv << 8) + (c << 5) + 8 * lg;
            short8 pa = *(const short8*)(pb + m0);
#pragma unroll
            for (int dt = 0; dt < 4; ++dt) {
                short8 vb = *(const short8*)(Vb + (size_t)(dt * 16 + lr) * 1024 + m0);
                o[dt] = __builtin_amdgcn_mfma_f32_16x16x32_bf16(pa, vb, o[dt], 0, 0, 0);
            }
        }
        float* lo = lds + 8192 + (wv << 10);   // scratch aliases consumed logits
#pragma unroll
        for (int dt = 0; dt < 4; ++dt)
#pragma unroll
            for (int j = 0; j < 4; ++j)
                lo[(4 * lg + j) * 64 + dt * 16 + lr] = o[dt][j];
    }
    __syncthreads();

    // ---- cross-wave reduce + coalesced store ----
#pragma unroll
    for (int i = 0; i < 4; ++i) {
        int idx = (i << 8) + tid;   // r*64 + d
        float s2 = lds[8192 + idx] + lds[8192 + 1024 + idx]
                 + lds[8192 + 2048 + idx] + lds[8192 + 3072 + idx];
        out[((size_t)bn0 << 6) + idx] = s2;
    }
}

extern "C" void kernel_launch(void* const* d_in, const int* in_sizes, int n_in,
                              void* d_out, int out_size, void* d_ws, size_t ws_size,
                              hipStream_t stream) {
    const float* x   = (const float*)d_in[0];
    const float* top = (const float*)d_in[1];
    const float* Wq  = (const float*)d_in[2];
    const float* bq  = (const float*)d_in[3];
    const float* Wk  = (const float*)d_in[4];
    const float* bk  = (const float*)d_in[5];
    const float* Wv  = (const float*)d_in[6];
    const float* bv  = (const float*)d_in[7];
    const float* Wt  = (const float*)d_in[8];
    // d_in[9] = bt: constant added to every logit -> softmax-invariant, dropped.
    float* out = (float*)d_out;

    ushort_t* Q    = (ushort_t*)d_ws;        // [8][1024][64] bf16 (pre-scaled 1/8)
    ushort_t* K    = Q + 8 * 1024 * 64;      // [8][1024][64] bf16
    ushort_t* Vt   = K + 8 * 1024 * 64;      // [8][64][1024] bf16 (transposed)
    ushort_t* bias = Vt + 8 * 1024 * 64;     // [8][1024][1024] bf16

    fused_bias_qkv<<<BIAS_BLOCKS + QKV_BLOCKS, 256, 0, stream>>>(
        x, top, Wq, bq, Wk, bk, Wv, bv, Wt, Q, K, Vt, bias);
    topo_attn<<<512, 256, 0, stream>>>(bias, Q, K, Vt, out);
}

// Round 10
// 175.322 us; speedup vs baseline: 3.3642x; 3.3642x over previous
//
#include <hip/hip_runtime.h>
#include <hip/hip_bf16.h>

typedef __attribute__((ext_vector_type(8))) short short8;
typedef __attribute__((ext_vector_type(4))) float f32x4;
typedef unsigned short ushort_t;
typedef unsigned int uint_t;

#define D_MODEL 512
#define D_ATTN  64
#define QKV_BLOCKS  512    // first in grid: 16 rows each, overlap under the stream
#define BIAS_BLOCKS 4096   // 4 wave-halfrows each -> 16384 halfrows = 8192 rows

__device__ __forceinline__ ushort_t f2bf(float f) {
    // round-to-nearest-even bf16 (finite inputs)
    uint_t u = __float_as_uint(f);
    u += 0x7FFFu + ((u >> 16) & 1u);
    return (ushort_t)(u >> 16);
}
__device__ __forceinline__ float bf2f(ushort_t h) {
    return __uint_as_float((uint_t)h << 16);
}
__device__ __forceinline__ f32x4 ntload4(const f32x4* p) {
    return __builtin_nontemporal_load(p);   // top read once
}

// ------- Kernel A: qkv head blocks + lean bias-stream blocks (NO vgpr cap) -------
__global__ __launch_bounds__(256)
void fused_bias_qkv(const float* __restrict__ x, const float* __restrict__ top,
                    const float* __restrict__ Wq, const float* __restrict__ bq,
                    const float* __restrict__ Wk, const float* __restrict__ bk,
                    const float* __restrict__ Wv, const float* __restrict__ bv,
                    const float* __restrict__ Wt,
                    ushort_t* __restrict__ Q, ushort_t* __restrict__ K,
                    ushort_t* __restrict__ Vt, ushort_t* __restrict__ bias)
{
    const int tid = threadIdx.x;
    const int l = tid & 63, w = tid >> 6;

    if (blockIdx.x < QKV_BLOCKS) {
        // ---- qkv (R4-verified body): 16 rows/block, wave w -> rows 4w..4w+3 ----
        const size_t bn0 = (size_t)blockIdx.x << 4;
        const int r0 = w << 2;
        const float* xb = x + (bn0 + r0) * D_MODEL;
        { uintptr_t u = (uintptr_t)xb; asm volatile("" : "+v"(u)); xb = (const float*)u; }

        float aq[4] = {0,0,0,0}, ak[4] = {0,0,0,0}, av[4] = {0,0,0,0};
#pragma unroll 2
        for (int k = 0; k < D_MODEL; k += 4) {
            float4 xr[4];
#pragma unroll
            for (int r = 0; r < 4; ++r) xr[r] = *(const float4*)(xb + r * D_MODEL + k);
            float wqv[4], wkv[4], wvv[4];
#pragma unroll
            for (int kk = 0; kk < 4; ++kk) {
                wqv[kk] = Wq[(k + kk) * D_ATTN + l];
                wkv[kk] = Wk[(k + kk) * D_ATTN + l];
                wvv[kk] = Wv[(k + kk) * D_ATTN + l];
            }
#pragma unroll
            for (int r = 0; r < 4; ++r) {
                const float xv[4] = {xr[r].x, xr[r].y, xr[r].z, xr[r].w};
#pragma unroll
                for (int kk = 0; kk < 4; ++kk) {
                    aq[r] = fmaf(xv[kk], wqv[kk], aq[r]);
                    ak[r] = fmaf(xv[kk], wkv[kk], ak[r]);
                    av[r] = fmaf(xv[kk], wvv[kk], av[r]);
                }
            }
        }
        const float bqv = bq[l], bkv = bk[l], bvv = bv[l];
#pragma unroll
        for (int r = 0; r < 4; ++r) {
            Q[(bn0 + r0 + r) * D_ATTN + l] = f2bf((aq[r] + bqv) * 0.125f); // fold 1/sqrt(64)
            K[(bn0 + r0 + r) * D_ATTN + l] = f2bf(ak[r] + bkv);
        }
        const int b = (int)(bn0 >> 10), n0loc = (int)(bn0 & 1023);
        uint2 pv;
        pv.x = (uint_t)f2bf(av[0] + bvv) | ((uint_t)f2bf(av[1] + bvv) << 16);
        pv.y = (uint_t)f2bf(av[2] + bvv) | ((uint_t)f2bf(av[3] + bvv) << 16);
        *(uint2*)(Vt + ((size_t)(b * 64 + l) << 10) + n0loc + r0) = pv;
    } else {
        // ---- bias: wave owns one contiguous 32KB half-row (512 outputs) ----
        const int h   = ((blockIdx.x - QKV_BLOCKS) << 2) + w;   // halfrow 0..16383
        const int row = h >> 1;                  // global (b*1024+n) 0..8191
        const int half = h & 1;
        const f32x4* __restrict__ gp =
            (const f32x4*)(top + ((size_t)row << 14) + ((size_t)half << 13)) + l;
        ushort_t* __restrict__ op = bias + ((size_t)row << 10) + (half << 9);
        const float4 wq = *(const float4*)(Wt + ((l & 3) << 2));  // my Wt quarter
        const int mq = l >> 2;
        const bool sel0 = (l & 3) == 0;
#pragma unroll 4
        for (int it = 0; it < 32; ++it) {
            f32x4 v = ntload4(gp + (it << 6));   // 64 lanes x 16B = 1KB contiguous
            float p = v[0] * wq.x;
            p = fmaf(v[1], wq.y, p);
            p = fmaf(v[2], wq.z, p);
            p = fmaf(v[3], wq.w, p);
            p += __shfl_xor(p, 1);               // fold quarters in 4-lane group
            p += __shfl_xor(p, 2);
            if (sel0) op[(it << 4) + mq] = f2bf(p);
        }
        // bt dropped: softmax shift-invariant
    }
}

// ---------------- Kernel B: attention from precomputed bias (R2-verified) ----------------
__global__ __launch_bounds__(256)
void topo_attn(const ushort_t* __restrict__ bias,
               const ushort_t* __restrict__ Q, const ushort_t* __restrict__ K,
               const ushort_t* __restrict__ Vt, float* __restrict__ out)
{
    __shared__ float lds[16384];
    const int tid = threadIdx.x;
    const int b   = blockIdx.x >> 6;
    const int bn0 = blockIdx.x << 4;   // b*1024 + n0

    // ---- Phase A': bias bf16 -> LDS logits f32 ----
    const ushort_t* __restrict__ bb = bias + ((size_t)bn0 << 10);
#pragma unroll
    for (int it = 0; it < 8; ++it) {
        int e0 = (it << 11) + (tid << 3);
        short8 v = *(const short8*)(bb + e0);
        f32x4 f0, f1;
#pragma unroll
        for (int j = 0; j < 4; ++j) f0[j] = bf2f((ushort_t)v[j]);
#pragma unroll
        for (int j = 0; j < 4; ++j) f1[j] = bf2f((ushort_t)v[4 + j]);
        *(f32x4*)(lds + e0)     = f0;
        *(f32x4*)(lds + e0 + 4) = f1;
    }
    __syncthreads();

    // ---- Phase B: logits += (Q/8) K^T via MFMA ----
    const int l = tid & 63, wv = tid >> 6;
    const int lr = l & 15, lg = l >> 4;
    const short8 a0 = *(const short8*)(Q + ((size_t)(bn0 + lr)) * 64 + 8 * lg);
    const short8 a1 = *(const short8*)(Q + ((size_t)(bn0 + lr)) * 64 + 32 + 8 * lg);
    const ushort_t* __restrict__ Kb = K + ((size_t)b << 16);
#pragma unroll 4
    for (int t16 = 0; t16 < 16; ++t16) {
        int m0 = (wv << 8) + (t16 << 4);
        short8 kb0 = *(const short8*)(Kb + (size_t)(m0 + lr) * 64 + 8 * lg);
        short8 kb1 = *(const short8*)(Kb + (size_t)(m0 + lr) * 64 + 32 + 8 * lg);
        f32x4 acc = {0.f, 0.f, 0.f, 0.f};
        acc = __builtin_amdgcn_mfma_f32_16x16x32_bf16(a0, kb0, acc, 0, 0, 0);
        acc = __builtin_amdgcn_mfma_f32_16x16x32_bf16(a1, kb1, acc, 0, 0, 0);
#pragma unroll
        for (int j = 0; j < 4; ++j)
            lds[(4 * lg + j) * 1024 + m0 + lr] += acc[j];  // C/D: col=lane&15, row=4*(l>>4)+j
    }
    __syncthreads();

    // ---- Phase C: row softmax; write P (bf16) aliased over logits[0:32KB) ----
    {
        const int r = tid >> 4, sseg = tid & 15;
        float4 v4[16];
        const float4* rowp = (const float4*)(lds + r * 1024 + sseg * 64);
#pragma unroll
        for (int i = 0; i < 16; ++i) v4[i] = rowp[i];
        __syncthreads();   // everyone finished reading logits before alias overwrite
        float mx = v4[0].x;
#pragma unroll
        for (int i = 0; i < 16; ++i)
            mx = fmaxf(mx, fmaxf(fmaxf(v4[i].x, v4[i].y), fmaxf(v4[i].z, v4[i].w)));
#pragma unroll
        for (int off = 8; off >= 1; off >>= 1) mx = fmaxf(mx, __shfl_xor(mx, off));
        float sum = 0.f;
#pragma unroll
        for (int i = 0; i < 16; ++i) {
            v4[i].x = __expf(v4[i].x - mx); sum += v4[i].x;
            v4[i].y = __expf(v4[i].y - mx); sum += v4[i].y;
            v4[i].z = __expf(v4[i].z - mx); sum += v4[i].z;
            v4[i].w = __expf(v4[i].w - mx); sum += v4[i].w;
        }
#pragma unroll
        for (int off = 8; off >= 1; off >>= 1) sum += __shfl_xor(sum, off);
        float inv = 1.0f / sum;
        ushort_t* pb = ((ushort_t*)lds) + r * 1024 + sseg * 64;
#pragma unroll
        for (int i = 0; i < 8; ++i) {
            uint_t w0 = (uint_t)f2bf(v4[2*i].x * inv)   | ((uint_t)f2bf(v4[2*i].y * inv)   << 16);
            uint_t w1 = (uint_t)f2bf(v4[2*i].z * inv)   | ((uint_t)f2bf(v4[2*i].w * inv)   << 16);
            uint_t w2 = (uint_t)f2bf(v4[2*i+1].x * inv) | ((uint_t)f2bf(v4[2*i+1].y * inv) << 16);
            uint_t w3 = (uint_t)f2bf(v4[2*i+1].z * inv) | ((uint_t)f2bf(v4[2*i+1].w * inv) << 16);
            ((uint4*)pb)[i] = make_uint4(w0, w1, w2, w3);
        }
    }
    __syncthreads();

    // ---- Phase D: out = P V  (V transposed -> contiguous B-frag loads) ----
    {
        f32x4 o[4] = {{0,0,0,0},{0,0,0,0},{0,0,0,0},{0,0,0,0}};
        const ushort_t* __restrict__ pb = ((const ushort_t*)lds) + lr * 1024;
        const ushort_t* __restrict__ Vb = Vt + ((size_t)b << 16);
#pragma unroll 2
        for (int c = 0; c < 8; ++c) {
            int m0 = (wv << 8) + (c << 5) + 8 * lg;
            short8 pa = *(const short8*)(pb + m0);
#pragma unroll
            for (int dt = 0; dt < 4; ++dt) {
                short8 vb = *(const short8*)(Vb + (size_t)(dt * 16 + lr) * 1024 + m0);
                o[dt] = __builtin_amdgcn_mfma_f32_16x16x32_bf16(pa, vb, o[dt], 0, 0, 0);
            }
        }
        float* lo = lds + 8192 + (wv << 10);   // scratch aliases consumed logits
#pragma unroll
        for (int dt = 0; dt < 4; ++dt)
#pragma unroll
            for (int j = 0; j < 4; ++j)
                lo[(4 * lg + j) * 64 + dt * 16 + lr] = o[dt][j];
    }
    __syncthreads();

    // ---- cross-wave reduce + coalesced store ----
#pragma unroll
    for (int i = 0; i < 4; ++i) {
        int idx = (i << 8) + tid;   // r*64 + d
        float s2 = lds[8192 + idx] + lds[8192 + 1024 + idx]
                 + lds[8192 + 2048 + idx] + lds[8192 + 3072 + idx];
        out[((size_t)bn0 << 6) + idx] = s2;
    }
}

extern "C" void kernel_launch(void* const* d_in, const int* in_sizes, int n_in,
                              void* d_out, int out_size, void* d_ws, size_t ws_size,
                              hipStream_t stream) {
    const float* x   = (const float*)d_in[0];
    const float* top = (const float*)d_in[1];
    const float* Wq  = (const float*)d_in[2];
    const float* bq  = (const float*)d_in[3];
    const float* Wk  = (const float*)d_in[4];
    const float* bk  = (const float*)d_in[5];
    const float* Wv  = (const float*)d_in[6];
    const float* bv  = (const float*)d_in[7];
    const float* Wt  = (const float*)d_in[8];
    // d_in[9] = bt: constant added to every logit -> softmax-invariant, dropped.
    float* out = (float*)d_out;

    ushort_t* Q    = (ushort_t*)d_ws;        // [8][1024][64] bf16 (pre-scaled 1/8)
    ushort_t* K    = Q + 8 * 1024 * 64;      // [8][1024][64] bf16
    ushort_t* Vt   = K + 8 * 1024 * 64;      // [8][64][1024] bf16 (transposed)
    ushort_t* bias = Vt + 8 * 1024 * 64;     // [8][1024][1024] bf16

    fused_bias_qkv<<<QKV_BLOCKS + BIAS_BLOCKS, 256, 0, stream>>>(
        x, top, Wq, bq, Wk, bk, Wv, bv, Wt, Q, K, Vt, bias);
    topo_attn<<<512, 256, 0, stream>>>(bias, Q, K, Vt, out);
}

// Round 11
// 160.850 us; speedup vs baseline: 3.6669x; 1.0900x over previous
//
#include <hip/hip_runtime.h>
#include <hip/hip_bf16.h>

typedef __attribute__((ext_vector_type(8))) short short8;
typedef __attribute__((ext_vector_type(4))) float f32x4;
typedef unsigned short ushort_t;
typedef unsigned int uint_t;

#define D_MODEL 512
#define D_ATTN  64

__device__ __forceinline__ ushort_t f2bf(float f) {
    // round-to-nearest-even bf16 (finite inputs)
    uint_t u = __float_as_uint(f);
    u += 0x7FFFu + ((u >> 16) & 1u);
    return (ushort_t)(u >> 16);
}
__device__ __forceinline__ f32x4 ntload4(const f32x4* p) {
    return __builtin_nontemporal_load(p);   // top is read exactly once: stream hint
}

// ---------------- Kernel 1: QKV, all components per wave (R4-exact) ----------------
__global__ __launch_bounds__(256)
void qkv_all(const float* __restrict__ x,
             const float* __restrict__ Wq, const float* __restrict__ bq,
             const float* __restrict__ Wk, const float* __restrict__ bk,
             const float* __restrict__ Wv, const float* __restrict__ bv,
             ushort_t* __restrict__ Q, ushort_t* __restrict__ K,
             ushort_t* __restrict__ Vt)
{
    const int l = threadIdx.x & 63, w = threadIdx.x >> 6;
    const size_t bn0 = (size_t)blockIdx.x << 4;
    const int r0 = w << 2;
    const float* xb = x + (bn0 + r0) * D_MODEL;
    { uintptr_t u = (uintptr_t)xb; asm volatile("" : "+v"(u)); xb = (const float*)u; }

    float aq[4] = {0,0,0,0}, ak[4] = {0,0,0,0}, av[4] = {0,0,0,0};
#pragma unroll 2
    for (int k = 0; k < D_MODEL; k += 4) {
        float4 xr[4];
#pragma unroll
        for (int r = 0; r < 4; ++r) xr[r] = *(const float4*)(xb + r * D_MODEL + k);
        float wqv[4], wkv[4], wvv[4];
#pragma unroll
        for (int kk = 0; kk < 4; ++kk) {
            wqv[kk] = Wq[(k + kk) * D_ATTN + l];
            wkv[kk] = Wk[(k + kk) * D_ATTN + l];
            wvv[kk] = Wv[(k + kk) * D_ATTN + l];
        }
#pragma unroll
        for (int r = 0; r < 4; ++r) {
            const float xv[4] = {xr[r].x, xr[r].y, xr[r].z, xr[r].w};
#pragma unroll
            for (int kk = 0; kk < 4; ++kk) {
                aq[r] = fmaf(xv[kk], wqv[kk], aq[r]);
                ak[r] = fmaf(xv[kk], wkv[kk], ak[r]);
                av[r] = fmaf(xv[kk], wvv[kk], av[r]);
            }
        }
    }
    const float bqv = bq[l], bkv = bk[l], bvv = bv[l];
#pragma unroll
    for (int r = 0; r < 4; ++r) {
        Q[(bn0 + r0 + r) * D_ATTN + l] = f2bf((aq[r] + bqv) * 0.125f); // fold 1/sqrt(64)
        K[(bn0 + r0 + r) * D_ATTN + l] = f2bf(ak[r] + bkv);
    }
    const int b = (int)(bn0 >> 10), n0loc = (int)(bn0 & 1023);
    uint2 pv;
    pv.x = (uint_t)f2bf(av[0] + bvv) | ((uint_t)f2bf(av[1] + bvv) << 16);
    pv.y = (uint_t)f2bf(av[2] + bvv) | ((uint_t)f2bf(av[3] + bvv) << 16);
    *(uint2*)(Vt + ((size_t)(b * 64 + l) << 10) + n0loc + r0) = pv;
}

// ---------------- Kernel 2: fused stream + attention (R7-exact) ----------------
// 512 blocks x 256 thr, 64KB LDS, 2 blocks/CU. Phase A: 16 independent NT
// f32x4 loads in flight per wave (16KB/wave, 128KB/CU), zero barriers.
__global__ __launch_bounds__(256)
void topo_attn_f(const float* __restrict__ top, const float* __restrict__ Wt,
                 const ushort_t* __restrict__ Q, const ushort_t* __restrict__ K,
                 const ushort_t* __restrict__ Vt, float* __restrict__ out)
{
    __shared__ float lds[16384];
    const int tid = threadIdx.x;
    const int l = tid & 63, wv = tid >> 6;
    const int b   = blockIdx.x >> 6;
    const int bn0 = blockIdx.x << 4;   // b*1024 + n0

    // ---- Phase A: bias[r][m] = top[bn0+r][m][:] . Wt  (537MB stream) ----
    {
        // wave slab = rows 4wv..4wv+3, contiguous 256KB, flat j = 0..255 (1KB/j)
        const f32x4* __restrict__ slab =
            (const f32x4*)top + ((size_t)bn0 << 12) + ((size_t)wv << 14) + l;
        const float4 wq = *(const float4*)(Wt + ((l & 3) << 2));  // my Wt quarter
        const int mq = l >> 2;
        const bool sel0 = (l & 3) == 0;
#pragma unroll 1
        for (int bi = 0; bi < 16; ++bi) {
            f32x4 ld[16];
#pragma unroll
            for (int u = 0; u < 16; ++u)
                ld[u] = ntload4(slab + (((bi << 4) + u) << 6));
#pragma unroll
            for (int u = 0; u < 16; ++u) {
                int j = (bi << 4) + u;
                float p = ld[u][0] * wq.x;
                p = fmaf(ld[u][1], wq.y, p);
                p = fmaf(ld[u][2], wq.z, p);
                p = fmaf(ld[u][3], wq.w, p);
                p += __shfl_xor(p, 1);     // fold quarters across 4-lane group
                p += __shfl_xor(p, 2);
                int m_slab = (j << 4) + mq;            // 0..4095 within slab
                int rloc = (wv << 2) + (m_slab >> 10); // local query row 0..15
                int m = m_slab & 1023;
                if (sel0) lds[rloc * 1024 + m] = p;    // 16 lanes -> 16 banks
            }
        }
        // bt dropped: softmax shift-invariant
    }
    __syncthreads();

    // ---- Phase B: logits += (Q/8) K^T via MFMA ----
    const int lr = l & 15, lg = l >> 4;
    const short8 a0 = *(const short8*)(Q + ((size_t)(bn0 + lr)) * 64 + 8 * lg);
    const short8 a1 = *(const short8*)(Q + ((size_t)(bn0 + lr)) * 64 + 32 + 8 * lg);
    const ushort_t* __restrict__ Kb = K + ((size_t)b << 16);
#pragma unroll 4
    for (int t16 = 0; t16 < 16; ++t16) {
        int m0 = (wv << 8) + (t16 << 4);
        short8 kb0 = *(const short8*)(Kb + (size_t)(m0 + lr) * 64 + 8 * lg);
        short8 kb1 = *(const short8*)(Kb + (size_t)(m0 + lr) * 64 + 32 + 8 * lg);
        f32x4 acc = {0.f, 0.f, 0.f, 0.f};
        acc = __builtin_amdgcn_mfma_f32_16x16x32_bf16(a0, kb0, acc, 0, 0, 0);
        acc = __builtin_amdgcn_mfma_f32_16x16x32_bf16(a1, kb1, acc, 0, 0, 0);
#pragma unroll
        for (int j = 0; j < 4; ++j)
            lds[(4 * lg + j) * 1024 + m0 + lr] += acc[j];  // C/D: col=lane&15, row=4*(l>>4)+j
    }
    __syncthreads();

    // ---- Phase C: row softmax; write P (bf16) aliased over logits[0:32KB) ----
    {
        const int r = tid >> 4, sseg = tid & 15;
        float4 v4[16];
        const float4* rowp = (const float4*)(lds + r * 1024 + sseg * 64);
#pragma unroll
        for (int i = 0; i < 16; ++i) v4[i] = rowp[i];
        __syncthreads();   // everyone finished reading logits before alias overwrite
        float mx = v4[0].x;
#pragma unroll
        for (int i = 0; i < 16; ++i)
            mx = fmaxf(mx, fmaxf(fmaxf(v4[i].x, v4[i].y), fmaxf(v4[i].z, v4[i].w)));
#pragma unroll
        for (int off = 8; off >= 1; off >>= 1) mx = fmaxf(mx, __shfl_xor(mx, off));
        float sum = 0.f;
#pragma unroll
        for (int i = 0; i < 16; ++i) {
            v4[i].x = __expf(v4[i].x - mx); sum += v4[i].x;
            v4[i].y = __expf(v4[i].y - mx); sum += v4[i].y;
            v4[i].z = __expf(v4[i].z - mx); sum += v4[i].z;
            v4[i].w = __expf(v4[i].w - mx); sum += v4[i].w;
        }
#pragma unroll
        for (int off = 8; off >= 1; off >>= 1) sum += __shfl_xor(sum, off);
        float inv = 1.0f / sum;
        ushort_t* pb = ((ushort_t*)lds) + r * 1024 + sseg * 64;
#pragma unroll
        for (int i = 0; i < 8; ++i) {
            uint_t w0 = (uint_t)f2bf(v4[2*i].x * inv)   | ((uint_t)f2bf(v4[2*i].y * inv)   << 16);
            uint_t w1 = (uint_t)f2bf(v4[2*i].z * inv)   | ((uint_t)f2bf(v4[2*i].w * inv)   << 16);
            uint_t w2 = (uint_t)f2bf(v4[2*i+1].x * inv) | ((uint_t)f2bf(v4[2*i+1].y * inv) << 16);
            uint_t w3 = (uint_t)f2bf(v4[2*i+1].z * inv) | ((uint_t)f2bf(v4[2*i+1].w * inv) << 16);
            ((uint4*)pb)[i] = make_uint4(w0, w1, w2, w3);
        }
    }
    __syncthreads();

    // ---- Phase D: out = P V  (V transposed -> contiguous B-frag loads) ----
    {
        f32x4 o[4] = {{0,0,0,0},{0,0,0,0},{0,0,0,0},{0,0,0,0}};
        const ushort_t* __restrict__ pb = ((const ushort_t*)lds) + lr * 1024;
        const ushort_t* __restrict__ Vb = Vt + ((size_t)b << 16);
#pragma unroll 2
        for (int c = 0; c < 8; ++c) {
            int m0 = (wv << 8) + (c << 5) + 8 * lg;
            short8 pa = *(const short8*)(pb + m0);
#pragma unroll
            for (int dt = 0; dt < 4; ++dt) {
                short8 vb = *(const short8*)(Vb + (size_t)(dt * 16 + lr) * 1024 + m0);
                o[dt] = __builtin_amdgcn_mfma_f32_16x16x32_bf16(pa, vb, o[dt], 0, 0, 0);
            }
        }
        float* lo = lds + 8192 + (wv << 10);   // scratch aliases consumed logits
#pragma unroll
        for (int dt = 0; dt < 4; ++dt)
#pragma unroll
            for (int j = 0; j < 4; ++j)
                lo[(4 * lg + j) * 64 + dt * 16 + lr] = o[dt][j];
    }
    __syncthreads();

    // ---- cross-wave reduce + coalesced store ----
#pragma unroll
    for (int i = 0; i < 4; ++i) {
        int idx = (i << 8) + tid;   // r*64 + d
        float s2 = lds[8192 + idx] + lds[8192 + 1024 + idx]
                 + lds[8192 + 2048 + idx] + lds[8192 + 3072 + idx];
        out[((size_t)bn0 << 6) + idx] = s2;
    }
}

extern "C" void kernel_launch(void* const* d_in, const int* in_sizes, int n_in,
                              void* d_out, int out_size, void* d_ws, size_t ws_size,
                              hipStream_t stream) {
    const float* x   = (const float*)d_in[0];
    const float* top = (const float*)d_in[1];
    const float* Wq  = (const float*)d_in[2];
    const float* bq  = (const float*)d_in[3];
    const float* Wk  = (const float*)d_in[4];
    const float* bk  = (const float*)d_in[5];
    const float* Wv  = (const float*)d_in[6];
    const float* bv  = (const float*)d_in[7];
    const float* Wt  = (const float*)d_in[8];
    // d_in[9] = bt: constant added to every logit -> softmax-invariant, dropped.
    float* out = (float*)d_out;

    ushort_t* Q  = (ushort_t*)d_ws;          // [8][1024][64] bf16 (pre-scaled 1/8)
    ushort_t* K  = Q + 8 * 1024 * 64;        // [8][1024][64] bf16
    ushort_t* Vt = K + 8 * 1024 * 64;        // [8][64][1024] bf16 (transposed)

    qkv_all<<<512, 256, 0, stream>>>(x, Wq, bq, Wk, bk, Wv, bv, Q, K, Vt);
    topo_attn_f<<<512, 256, 0, stream>>>(top, Wt, Q, K, Vt, out);
}